// Round 6
// baseline (146.475 us; speedup 1.0000x reference)
//
#include <hip/hip_runtime.h>
#include <hip/hip_bf16.h>

typedef float f4 __attribute__((ext_vector_type(4)));
typedef unsigned int u32;
typedef u32 u4 __attribute__((ext_vector_type(4)));

constexpr int B = 2, C = 16, D = 24, H = 48, W = 48;
constexpr int K = 27;
constexpr int SP = D * H * W;   // 55296 (divisible by 128)
constexpr int HW = H * W;

__device__ inline ushort bf16_bits(float f) {
    __hip_bfloat16 h = __float2bfloat16(f);   // RTN-E
    return __builtin_bit_cast(ushort, h);
}

// x [B,C,S] f32 -> xt [B,S,16ch] bf16 (32 B per spatial point)  — EXACT R3 copy
__global__ __launch_bounds__(256) void xpose_bf16_kernel(const float* __restrict__ x,
                                                         u32* __restrict__ xt) {
    int t = blockIdx.x * blockDim.x + threadIdx.x;
    if (t >= B * SP) return;
    int s = t % SP, b = t / SP;
    const float* src = x + (size_t)b * C * SP + s;
    u4 pk[2];
#pragma unroll
    for (int m = 0; m < 8; ++m) {
        float lo = src[(size_t)(2 * m) * SP];
        float hi = src[(size_t)(2 * m + 1) * SP];
        pk[m >> 2][m & 3] = (u32)bf16_bits(lo) | ((u32)bf16_bits(hi) << 16);
    }
    u4* dst = reinterpret_cast<u4*>(xt + (size_t)t * 8);
    dst[0] = pk[0];
    dst[1] = pk[1];
}

// thread = (b, khalf, p, q): R3's exact per-tap math, looped over 13/14 taps.
__global__ __launch_bounds__(256, 8) void deform_bf16_k(const u32* __restrict__ xt,
                                                        const float* __restrict__ off,
                                                        float* __restrict__ out) {
    const int tid = blockIdx.x * blockDim.x + threadIdx.x;
    const int q = tid & 1;
    const int t = tid >> 1;
    const int p = t % SP;
    const int r = t / SP;       // 0..3, block-uniform (SP % 128 == 0)
    const int khalf = r & 1;
    const int b = r >> 1;

    const int od = p / HW;
    const int rem = p - od * HW;
    const int oh = rem / W, ow = rem - oh * W;

    const float* obp = off + (size_t)b * (3 * K) * SP + p;
    const u4* xb = reinterpret_cast<const u4*>(xt) + (size_t)b * SP * 2 + q;

    __shared__ float lds[2][4][16][36];         // [parity][wave][ch][p+pad]
    const int l = threadIdx.x & 63;
    const int wv = threadIdx.x >> 6;
    const int c = l >> 1;                       // p-local 0..31
    const size_t p_base = (size_t)(p - c);      // 32-aligned, wave-uniform
    const int ch_lo = l >> 3;                   // 0..7
    const int p0 = 4 * (l & 7);
    float* osb = out + ((size_t)b * C * K) * SP + p_base + p0;

    const int k_beg = khalf ? 14 : 0;
    const int k_end = khalf ? 27 : 14;
#pragma unroll 2
    for (int k = k_beg; k < k_end; ++k) {
        const int ki = k / 9, kr2 = k - ki * 9;
        const int kj = kr2 / 3, kk = kr2 - kj * 3;

        float offd = __builtin_nontemporal_load(obp + (size_t)(3 * k) * SP);
        float offh = __builtin_nontemporal_load(obp + (size_t)(3 * k + 1) * SP);
        float offw = __builtin_nontemporal_load(obp + (size_t)(3 * k + 2) * SP);

        float pd = (float)(od + ki - 1) + offd;
        float ph = (float)(oh + kj - 1) + offh;
        float pw = (float)(ow + kk - 1) + offw;

        float d0f = floorf(pd), h0f = floorf(ph), w0f = floorf(pw);
        float fd = pd - d0f, fh = ph - h0f, fw = pw - w0f;
        int d0 = (int)d0f, h0 = (int)h0f, w0 = (int)w0f;

        float acc[8] = {};
#pragma unroll
        for (int ci = 0; ci < 2; ++ci) {
            int ds = d0 + ci;
            bool vd = (ds >= 0) & (ds < D);
            float wd = ci ? fd : 1.0f - fd;
            int dc = min(max(ds, 0), D - 1);
#pragma unroll
            for (int cj = 0; cj < 2; ++cj) {
                int hs = h0 + cj;
                bool vh = (hs >= 0) & (hs < H);
                float wh = cj ? fh : 1.0f - fh;
                int hc = min(max(hs, 0), H - 1);
#pragma unroll
                for (int ck = 0; ck < 2; ++ck) {
                    int ws = w0 + ck;
                    bool vw = (ws >= 0) & (ws < W);
                    float ww = ck ? fw : 1.0f - fw;
                    int wc = min(max(ws, 0), W - 1);
                    float wgt = (vd & vh & vw) ? wd * wh * ww : 0.0f;
                    int idx = (dc * H + hc) * W + wc;
                    u4 v = xb[(size_t)idx * 2];
#pragma unroll
                    for (int m = 0; m < 4; ++m) {
                        u32 wbits = v[m];
                        float lo = __builtin_bit_cast(float, wbits << 16);
                        float hi = __builtin_bit_cast(float, wbits & 0xffff0000u);
                        acc[2 * m] += wgt * lo;
                        acc[2 * m + 1] += wgt * hi;
                    }
                }
            }
        }

        float(*tile)[36] = lds[k & 1][wv];
#pragma unroll
        for (int j = 0; j < 8; ++j) tile[8 * q + j][c] = acc[j];
        __syncthreads();
#pragma unroll
        for (int rr = 0; rr < 2; ++rr) {
            int ch = 8 * rr + ch_lo;
            f4 vv = *reinterpret_cast<const f4*>(&tile[ch][p0]);
            *reinterpret_cast<f4*>(osb + ((size_t)ch * K + k) * SP) = vv;
        }
    }
}

// fallback (no workspace): one thread per sample, gather from native fp32 layout
__global__ __launch_bounds__(256) void deform_kernel_nat(const float* __restrict__ x,
                                                         const float* __restrict__ off,
                                                         float* __restrict__ out) {
    int tid = blockIdx.x * blockDim.x + threadIdx.x;
    if (tid >= B * K * SP) return;
    int p = tid % SP;
    int bk = tid / SP;
    int k = bk % K, b = bk / K;

    const float* ob = off + ((size_t)b * (3 * K) + 3 * k) * SP + p;
    float offd = ob[0];
    float offh = ob[(size_t)SP];
    float offw = ob[(size_t)2 * SP];

    int od = p / HW, rem = p - od * HW;
    int oh = rem / W, ow = rem - oh * W;
    int ki = k / 9, kr = k - ki * 9;
    int kj = kr / 3, kk = kr - kj * 3;

    float pd = (float)(od + ki - 1) + offd;
    float ph = (float)(oh + kj - 1) + offh;
    float pw = (float)(ow + kk - 1) + offw;

    float d0f = floorf(pd), h0f = floorf(ph), w0f = floorf(pw);
    float fd = pd - d0f, fh = ph - h0f, fw = pw - w0f;
    int d0 = (int)d0f, h0 = (int)h0f, w0 = (int)w0f;

    f4 acc[4] = {};
#pragma unroll
    for (int ci = 0; ci < 2; ++ci) {
        int ds = d0 + ci;
        bool vd = (ds >= 0) & (ds < D);
        float wd = ci ? fd : 1.0f - fd;
        int dc = min(max(ds, 0), D - 1);
#pragma unroll
        for (int cj = 0; cj < 2; ++cj) {
            int hs = h0 + cj;
            bool vh = (hs >= 0) & (hs < H);
            float wh = cj ? fh : 1.0f - fh;
            int hc = min(max(hs, 0), H - 1);
#pragma unroll
            for (int ck = 0; ck < 2; ++ck) {
                int ws = w0 + ck;
                bool vw = (ws >= 0) & (ws < W);
                float ww = ck ? fw : 1.0f - fw;
                int wc = min(max(ws, 0), W - 1);
                float wgt = (vd & vh & vw) ? wd * wh * ww : 0.0f;
                int idx = (dc * H + hc) * W + wc;
                const float* src = x + (size_t)b * C * SP + idx;
#pragma unroll
                for (int c2 = 0; c2 < C; ++c2)
                    acc[c2 >> 2][c2 & 3] += wgt * src[(size_t)c2 * SP];
            }
        }
    }

    float* o = out + ((size_t)b * C * K + k) * SP + p;
#pragma unroll
    for (int c2 = 0; c2 < C; ++c2)
        o[(size_t)c2 * K * SP] = acc[c2 >> 2][c2 & 3];
}

extern "C" void kernel_launch(void* const* d_in, const int* in_sizes, int n_in,
                              void* d_out, int out_size, void* d_ws, size_t ws_size,
                              hipStream_t stream) {
    const float* x = (const float*)d_in[0];
    const float* off = (const float*)d_in[1];
    float* out = (float*)d_out;

    const size_t xt_bytes = (size_t)B * SP * 16 * sizeof(ushort);  // 3.5 MB

    if (ws_size >= xt_bytes) {
        u32* xt = (u32*)d_ws;
        const int n_x = B * SP;
        xpose_bf16_kernel<<<(n_x + 255) / 256, 256, 0, stream>>>(x, xt);
        const long long n_thr = (long long)B * SP * 2 * 2;   // 442,368
        const int grid = (int)(n_thr / 256);                 // 1728, exact
        deform_bf16_k<<<grid, 256, 0, stream>>>(xt, off, out);
    } else {
        const int n_main = B * K * SP;
        deform_kernel_nat<<<(n_main + 255) / 256, 256, 0, stream>>>(x, off, out);
    }
}

// Round 7
// 135.943 us; speedup vs baseline: 1.0775x; 1.0775x over previous
//
#include <hip/hip_runtime.h>
#include <hip/hip_bf16.h>

typedef float f4 __attribute__((ext_vector_type(4)));
typedef unsigned int u32;
typedef u32 u4 __attribute__((ext_vector_type(4)));

constexpr int B = 2, C = 16, D = 24, H = 48, W = 48;
constexpr int K = 27;
constexpr int SP = D * H * W;   // 55296 (divisible by 256)
constexpr int HW = H * W;

__device__ inline ushort bf16_bits(float f) {
    __hip_bfloat16 h = __float2bfloat16(f);   // RTN-E
    return __builtin_bit_cast(ushort, h);
}

// x [B,C,S] f32 -> xt [B,S,16ch] bf16 (32 B per spatial point)
__global__ __launch_bounds__(256) void xpose_bf16_kernel(const float* __restrict__ x,
                                                         u32* __restrict__ xt) {
    int t = blockIdx.x * blockDim.x + threadIdx.x;
    if (t >= B * SP) return;
    int s = t % SP, b = t / SP;
    const float* src = x + (size_t)b * C * SP + s;
    u4 pk[2];
#pragma unroll
    for (int m = 0; m < 8; ++m) {
        float lo = src[(size_t)(2 * m) * SP];
        float hi = src[(size_t)(2 * m + 1) * SP];
        pk[m >> 2][m & 3] = (u32)bf16_bits(lo) | ((u32)bf16_bits(hi) << 16);
    }
    u4* dst = reinterpret_cast<u4*>(xt + (size_t)t * 8);
    dst[0] = pk[0];
    dst[1] = pk[1];
}

// One thread per (b,k,p) sample, all 16 channels. R3's exact per-tap math.
// Wave = 64 consecutive p at fixed (b,k) -> gathers cluster into contiguous runs.
__global__ __launch_bounds__(256, 4) void deform_bf16_c16(const u32* __restrict__ xt,
                                                          const float* __restrict__ off,
                                                          float* __restrict__ out) {
    const int tid = blockIdx.x * blockDim.x + threadIdx.x;
    const int p = tid % SP;
    const int bk = tid / SP;        // block-uniform (SP % 256 == 0)
    const int k = bk % K, b = bk / K;

    const int od = p / HW;
    const int rem = p - od * HW;
    const int oh = rem / W, ow = rem - oh * W;
    const int ki = k / 9, kr2 = k - ki * 9;
    const int kj = kr2 / 3, kk = kr2 - kj * 3;

    const float* ob = off + ((size_t)b * (3 * K) + 3 * k) * SP + p;
    float offd = __builtin_nontemporal_load(ob);
    float offh = __builtin_nontemporal_load(ob + (size_t)SP);
    float offw = __builtin_nontemporal_load(ob + (size_t)2 * SP);

    float pd = (float)(od + ki - 1) + offd;
    float ph = (float)(oh + kj - 1) + offh;
    float pw = (float)(ow + kk - 1) + offw;

    float d0f = floorf(pd), h0f = floorf(ph), w0f = floorf(pw);
    float fd = pd - d0f, fh = ph - h0f, fw = pw - w0f;
    int d0 = (int)d0f, h0 = (int)h0f, w0 = (int)w0f;

    const u4* xb = reinterpret_cast<const u4*>(xt) + (size_t)b * SP * 2;

    float acc[16] = {};
#pragma unroll
    for (int ci = 0; ci < 2; ++ci) {
        int ds = d0 + ci;
        bool vd = (ds >= 0) & (ds < D);
        float wd = ci ? fd : 1.0f - fd;
        int dc = min(max(ds, 0), D - 1);
#pragma unroll
        for (int cj = 0; cj < 2; ++cj) {
            int hs = h0 + cj;
            bool vh = (hs >= 0) & (hs < H);
            float wh = cj ? fh : 1.0f - fh;
            int hc = min(max(hs, 0), H - 1);
#pragma unroll
            for (int ck = 0; ck < 2; ++ck) {
                int ws = w0 + ck;
                bool vw = (ws >= 0) & (ws < W);
                float ww = ck ? fw : 1.0f - fw;
                int wc = min(max(ws, 0), W - 1);
                float wgt = (vd & vh & vw) ? wd * wh * ww : 0.0f;
                int idx = (dc * H + hc) * W + wc;
                const u4* rec = xb + (size_t)idx * 2;
                u4 v0 = rec[0];
                u4 v1 = rec[1];
#pragma unroll
                for (int m = 0; m < 4; ++m) {
                    u32 wb = v0[m];
                    acc[2 * m]     += wgt * __builtin_bit_cast(float, wb << 16);
                    acc[2 * m + 1] += wgt * __builtin_bit_cast(float, wb & 0xffff0000u);
                }
#pragma unroll
                for (int m = 0; m < 4; ++m) {
                    u32 wb = v1[m];
                    acc[8 + 2 * m] += wgt * __builtin_bit_cast(float, wb << 16);
                    acc[9 + 2 * m] += wgt * __builtin_bit_cast(float, wb & 0xffff0000u);
                }
            }
        }
    }

    // wave-local transpose: [p(64)][ch] -> [ch][p] so stores are 256B-contiguous runs
    __shared__ float tile[4][16][68];           // 68-pad keeps rows 16B-aligned
    const int l = threadIdx.x & 63;
    const int wv = threadIdx.x >> 6;
#pragma unroll
    for (int j = 0; j < 16; ++j) tile[wv][j][l] = acc[j];
    __syncthreads();

    const int p_base = p - l;                   // wave-uniform, 64-aligned
    const int colbase = 4 * (l & 15);
    const int choff = l >> 4;                   // 0..3
#pragma unroll
    for (int pass = 0; pass < 4; ++pass) {
        int ch = pass * 4 + choff;
        f4 vv = *reinterpret_cast<const f4*>(&tile[wv][ch][colbase]);
        *reinterpret_cast<f4*>(out + (((size_t)b * C + ch) * K + k) * SP + p_base + colbase) = vv;
    }
}

// fallback (no workspace): one thread per sample, gather from native fp32 layout
__global__ __launch_bounds__(256) void deform_kernel_nat(const float* __restrict__ x,
                                                         const float* __restrict__ off,
                                                         float* __restrict__ out) {
    int tid = blockIdx.x * blockDim.x + threadIdx.x;
    if (tid >= B * K * SP) return;
    int p = tid % SP;
    int bk = tid / SP;
    int k = bk % K, b = bk / K;

    const float* ob = off + ((size_t)b * (3 * K) + 3 * k) * SP + p;
    float offd = ob[0];
    float offh = ob[(size_t)SP];
    float offw = ob[(size_t)2 * SP];

    int od = p / HW, rem = p - od * HW;
    int oh = rem / W, ow = rem - oh * W;
    int ki = k / 9, kr = k - ki * 9;
    int kj = kr / 3, kk = kr - kj * 3;

    float pd = (float)(od + ki - 1) + offd;
    float ph = (float)(oh + kj - 1) + offh;
    float pw = (float)(ow + kk - 1) + offw;

    float d0f = floorf(pd), h0f = floorf(ph), w0f = floorf(pw);
    float fd = pd - d0f, fh = ph - h0f, fw = pw - w0f;
    int d0 = (int)d0f, h0 = (int)h0f, w0 = (int)w0f;

    f4 acc[4] = {};
#pragma unroll
    for (int ci = 0; ci < 2; ++ci) {
        int ds = d0 + ci;
        bool vd = (ds >= 0) & (ds < D);
        float wd = ci ? fd : 1.0f - fd;
        int dc = min(max(ds, 0), D - 1);
#pragma unroll
        for (int cj = 0; cj < 2; ++cj) {
            int hs = h0 + cj;
            bool vh = (hs >= 0) & (hs < H);
            float wh = cj ? fh : 1.0f - fh;
            int hc = min(max(hs, 0), H - 1);
#pragma unroll
            for (int ck = 0; ck < 2; ++ck) {
                int ws = w0 + ck;
                bool vw = (ws >= 0) & (ws < W);
                float ww = ck ? fw : 1.0f - fw;
                int wc = min(max(ws, 0), W - 1);
                float wgt = (vd & vh & vw) ? wd * wh * ww : 0.0f;
                int idx = (dc * H + hc) * W + wc;
                const float* src = x + (size_t)b * C * SP + idx;
#pragma unroll
                for (int c2 = 0; c2 < C; ++c2)
                    acc[c2 >> 2][c2 & 3] += wgt * src[(size_t)c2 * SP];
            }
        }
    }

    float* o = out + ((size_t)b * C * K + k) * SP + p;
#pragma unroll
    for (int c2 = 0; c2 < C; ++c2)
        o[(size_t)c2 * K * SP] = acc[c2 >> 2][c2 & 3];
}

extern "C" void kernel_launch(void* const* d_in, const int* in_sizes, int n_in,
                              void* d_out, int out_size, void* d_ws, size_t ws_size,
                              hipStream_t stream) {
    const float* x = (const float*)d_in[0];
    const float* off = (const float*)d_in[1];
    float* out = (float*)d_out;

    const size_t xt_bytes = (size_t)B * SP * 16 * sizeof(ushort);  // 3.5 MB

    if (ws_size >= xt_bytes) {
        u32* xt = (u32*)d_ws;
        const int n_x = B * SP;
        xpose_bf16_kernel<<<(n_x + 255) / 256, 256, 0, stream>>>(x, xt);
        const int n_main = B * K * SP;          // 2,985,984
        const int grid = n_main / 256;          // 11664, exact
        deform_bf16_c16<<<grid, 256, 0, stream>>>(xt, off, out);
    } else {
        const int n_main = B * K * SP;
        deform_kernel_nat<<<(n_main + 255) / 256, 256, 0, stream>>>(x, off, out);
    }
}

// Round 8
// 112.332 us; speedup vs baseline: 1.3039x; 1.2102x over previous
//
#include <hip/hip_runtime.h>
#include <hip/hip_bf16.h>

typedef float f4 __attribute__((ext_vector_type(4)));
typedef float f2 __attribute__((ext_vector_type(2)));
typedef unsigned int u32;
typedef u32 u4 __attribute__((ext_vector_type(4)));

constexpr int B = 2, C = 16, D = 24, H = 48, W = 48;
constexpr int K = 27;
constexpr int SP = D * H * W;   // 55296 (divisible by 128)
constexpr int HW = H * W;

__device__ inline ushort bf16_bits(float f) {
    __hip_bfloat16 h = __float2bfloat16(f);   // RTN-E
    return __builtin_bit_cast(ushort, h);
}

// x [B,C,S] f32 -> xt [B,S,16ch] bf16 (32 B per spatial point)
__global__ __launch_bounds__(256) void xpose_bf16_kernel(const float* __restrict__ x,
                                                         u32* __restrict__ xt) {
    int t = blockIdx.x * blockDim.x + threadIdx.x;
    if (t >= B * SP) return;
    int s = t % SP, b = t / SP;
    const float* src = x + (size_t)b * C * SP + s;
    u4 pk[2];
#pragma unroll
    for (int m = 0; m < 8; ++m) {
        float lo = src[(size_t)(2 * m) * SP];
        float hi = src[(size_t)(2 * m + 1) * SP];
        pk[m >> 2][m & 3] = (u32)bf16_bits(lo) | ((u32)bf16_bits(hi) << 16);
    }
    u4* dst = reinterpret_cast<u4*>(xt + (size_t)t * 8);
    dst[0] = pk[0];
    dst[1] = pk[1];
}

// R3 structure, split-half lanes: wave = 32 samples x 2 channel-halves.
// q = l>>5 (channel half), c = l&31 (sample). Offset loads coalesced + shfl.
__global__ __launch_bounds__(256, 8) void deform_bf16_v8(const u32* __restrict__ xt,
                                                         const float* __restrict__ off,
                                                         float* __restrict__ out) {
    const int tid = blockIdx.x * blockDim.x + threadIdx.x;
    const int l = threadIdx.x & 63;
    const int q = l >> 5;                    // channel half 0/1
    const int c = l & 31;                    // sample-in-wave 0..31
    const int s = (tid >> 6) * 32 + c;       // global sample id
    const int p = s % SP;
    const int bk = s / SP;                   // wave-uniform (SP % 32 == 0)
    const int k = bk % K, b = bk / K;

    // ---- offsets: 1 full-wave + 1 half-wave coalesced load, then shfl ----
    const size_t obase = ((size_t)b * (3 * K) + 3 * k) * SP;
    float vdh = __builtin_nontemporal_load(off + obase + (size_t)q * SP + p);
    float vw = 0.0f;
    if (l < 32) vw = __builtin_nontemporal_load(off + obase + (size_t)2 * SP + p);
    float offd = __shfl(vdh, c);
    float offh = __shfl(vdh, c + 32);
    float offw = __shfl(vw, c);

    const int od = p / HW;
    const int rem = p - od * HW;
    const int oh = rem / W, ow = rem - oh * W;
    const int ki = k / 9, kr2 = k - ki * 9;
    const int kj = kr2 / 3, kk = kr2 - kj * 3;

    float pd = (float)(od + ki - 1) + offd;
    float ph = (float)(oh + kj - 1) + offh;
    float pw = (float)(ow + kk - 1) + offw;

    float d0f = floorf(pd), h0f = floorf(ph), w0f = floorf(pw);
    float fd = pd - d0f, fh = ph - h0f, fw = pw - w0f;
    int d0 = (int)d0f, h0 = (int)h0f, w0 = (int)w0f;

    const u4* xb = reinterpret_cast<const u4*>(xt) + (size_t)b * SP * 2 + q;

    f2 acc[4] = {};
#pragma unroll
    for (int ci = 0; ci < 2; ++ci) {
        int ds = d0 + ci;
        bool vd = (ds >= 0) & (ds < D);
        float wd = ci ? fd : 1.0f - fd;
        int dc = min(max(ds, 0), D - 1);
#pragma unroll
        for (int cj = 0; cj < 2; ++cj) {
            int hs = h0 + cj;
            bool vh = (hs >= 0) & (hs < H);
            float wh = cj ? fh : 1.0f - fh;
            int hc = min(max(hs, 0), H - 1);
#pragma unroll
            for (int ck = 0; ck < 2; ++ck) {
                int ws = w0 + ck;
                bool vw2 = (ws >= 0) & (ws < W);
                float ww = ck ? fw : 1.0f - fw;
                int wc = min(max(ws, 0), W - 1);
                float wgt = (vd & vh & vw2) ? wd * wh * ww : 0.0f;
                f2 w2 = {wgt, wgt};
                int idx = (dc * H + hc) * W + wc;
                u4 v = xb[(size_t)idx * 2];
#pragma unroll
                for (int m = 0; m < 4; ++m) {
                    u32 wb = v[m];
                    f2 xv = {__builtin_bit_cast(float, wb << 16),
                             __builtin_bit_cast(float, wb & 0xffff0000u)};
                    acc[m] += w2 * xv;
                }
            }
        }
    }

    // wave-local transpose: [ch16][sample32] -> stores are 8 x 128B full lines/inst
    __shared__ float tile[4][16][36];
    const int wv = threadIdx.x >> 6;
#pragma unroll
    for (int m = 0; m < 4; ++m) {
        tile[wv][8 * q + 2 * m][c] = acc[m][0];
        tile[wv][8 * q + 2 * m + 1][c] = acc[m][1];
    }
    __syncthreads();

    const int p_base = p - c;                 // wave-uniform, 32-aligned
    const int ch_lo = l >> 3;                 // 0..7
    const int p0 = 4 * (l & 7);
    float* osb = out + ((size_t)b * C * K) * SP + p_base + p0;
#pragma unroll
    for (int rr = 0; rr < 2; ++rr) {
        int ch = 8 * rr + ch_lo;
        f4 vv = *reinterpret_cast<const f4*>(&tile[wv][ch][p0]);
        *reinterpret_cast<f4*>(osb + ((size_t)ch * K + k) * SP) = vv;
    }
}

// fallback (no workspace): one thread per sample, gather from native fp32 layout
__global__ __launch_bounds__(256) void deform_kernel_nat(const float* __restrict__ x,
                                                         const float* __restrict__ off,
                                                         float* __restrict__ out) {
    int tid = blockIdx.x * blockDim.x + threadIdx.x;
    if (tid >= B * K * SP) return;
    int p = tid % SP;
    int bk = tid / SP;
    int k = bk % K, b = bk / K;

    const float* ob = off + ((size_t)b * (3 * K) + 3 * k) * SP + p;
    float offd = ob[0];
    float offh = ob[(size_t)SP];
    float offw = ob[(size_t)2 * SP];

    int od = p / HW, rem = p - od * HW;
    int oh = rem / W, ow = rem - oh * W;
    int ki = k / 9, kr = k - ki * 9;
    int kj = kr / 3, kk = kr - kj * 3;

    float pd = (float)(od + ki - 1) + offd;
    float ph = (float)(oh + kj - 1) + offh;
    float pw = (float)(ow + kk - 1) + offw;

    float d0f = floorf(pd), h0f = floorf(ph), w0f = floorf(pw);
    float fd = pd - d0f, fh = ph - h0f, fw = pw - w0f;
    int d0 = (int)d0f, h0 = (int)h0f, w0 = (int)w0f;

    f4 acc[4] = {};
#pragma unroll
    for (int ci = 0; ci < 2; ++ci) {
        int ds = d0 + ci;
        bool vd = (ds >= 0) & (ds < D);
        float wd = ci ? fd : 1.0f - fd;
        int dc = min(max(ds, 0), D - 1);
#pragma unroll
        for (int cj = 0; cj < 2; ++cj) {
            int hs = h0 + cj;
            bool vh = (hs >= 0) & (hs < H);
            float wh = cj ? fh : 1.0f - fh;
            int hc = min(max(hs, 0), H - 1);
#pragma unroll
            for (int ck = 0; ck < 2; ++ck) {
                int ws = w0 + ck;
                bool vw = (ws >= 0) & (ws < W);
                float ww = ck ? fw : 1.0f - fw;
                int wc = min(max(ws, 0), W - 1);
                float wgt = (vd & vh & vw) ? wd * wh * ww : 0.0f;
                int idx = (dc * H + hc) * W + wc;
                const float* src = x + (size_t)b * C * SP + idx;
#pragma unroll
                for (int c2 = 0; c2 < C; ++c2)
                    acc[c2 >> 2][c2 & 3] += wgt * src[(size_t)c2 * SP];
            }
        }
    }

    float* o = out + ((size_t)b * C * K + k) * SP + p;
#pragma unroll
    for (int c2 = 0; c2 < C; ++c2)
        o[(size_t)c2 * K * SP] = acc[c2 >> 2][c2 & 3];
}

extern "C" void kernel_launch(void* const* d_in, const int* in_sizes, int n_in,
                              void* d_out, int out_size, void* d_ws, size_t ws_size,
                              hipStream_t stream) {
    const float* x = (const float*)d_in[0];
    const float* off = (const float*)d_in[1];
    float* out = (float*)d_out;

    const size_t xt_bytes = (size_t)B * SP * 16 * sizeof(ushort);  // 3.5 MB

    if (ws_size >= xt_bytes) {
        u32* xt = (u32*)d_ws;
        const int n_x = B * SP;
        xpose_bf16_kernel<<<(n_x + 255) / 256, 256, 0, stream>>>(x, xt);
        const long long n_thr = (long long)B * K * SP * 2;   // 5,971,968
        const int grid = (int)(n_thr / 256);                 // 23328, exact
        deform_bf16_v8<<<grid, 256, 0, stream>>>(xt, off, out);
    } else {
        const int n_main = B * K * SP;
        deform_kernel_nat<<<(n_main + 255) / 256, 256, 0, stream>>>(x, off, out);
    }
}

// Round 9
// 106.164 us; speedup vs baseline: 1.3797x; 1.0581x over previous
//
#include <hip/hip_runtime.h>
#include <hip/hip_bf16.h>

typedef float f4 __attribute__((ext_vector_type(4)));
typedef float f2 __attribute__((ext_vector_type(2)));
typedef unsigned int u32;
typedef u32 u4 __attribute__((ext_vector_type(4)));

constexpr int B = 2, C = 16, D = 24, H = 48, W = 48;
constexpr int K = 27;
constexpr int SP = D * H * W;   // 55296 (divisible by 128)
constexpr int HW = H * W;

__device__ inline ushort bf16_bits(float f) {
    __hip_bfloat16 h = __float2bfloat16(f);   // RTN-E
    return __builtin_bit_cast(ushort, h);
}

// x [B,C,S] f32 -> xt [B,S,16ch] bf16 (32 B per spatial point)
__global__ __launch_bounds__(256) void xpose_bf16_kernel(const float* __restrict__ x,
                                                         u32* __restrict__ xt) {
    int t = blockIdx.x * blockDim.x + threadIdx.x;
    if (t >= B * SP) return;
    int s = t % SP, b = t / SP;
    const float* src = x + (size_t)b * C * SP + s;
    u4 pk[2];
#pragma unroll
    for (int m = 0; m < 8; ++m) {
        float lo = src[(size_t)(2 * m) * SP];
        float hi = src[(size_t)(2 * m + 1) * SP];
        pk[m >> 2][m & 3] = (u32)bf16_bits(lo) | ((u32)bf16_bits(hi) << 16);
    }
    u4* dst = reinterpret_cast<u4*>(xt + (size_t)t * 8);
    dst[0] = pk[0];
    dst[1] = pk[1];
}

// R8 mapping (wave = 32 samples x 2 channel-halves) + all-8-gathers-in-flight.
__global__ __launch_bounds__(256, 4) void deform_bf16_v9(const u32* __restrict__ xt,
                                                         const float* __restrict__ off,
                                                         float* __restrict__ out) {
    const int tid = blockIdx.x * blockDim.x + threadIdx.x;
    const int l = threadIdx.x & 63;
    const int q = l >> 5;                    // channel half 0/1
    const int c = l & 31;                    // sample-in-wave 0..31
    const int s = (tid >> 6) * 32 + c;       // global sample id
    const int p = s % SP;
    const int bk = s / SP;                   // wave-uniform (SP % 32 == 0)
    const int k = bk % K, b = bk / K;

    // offsets: 1 full-wave + 1 half-wave coalesced load, then shfl broadcast
    const size_t obase = ((size_t)b * (3 * K) + 3 * k) * SP;
    float vdh = __builtin_nontemporal_load(off + obase + (size_t)q * SP + p);
    float vw = 0.0f;
    if (l < 32) vw = __builtin_nontemporal_load(off + obase + (size_t)2 * SP + p);
    float offd = __shfl(vdh, c);
    float offh = __shfl(vdh, c + 32);
    float offw = __shfl(vw, c);

    const int od = p / HW;
    const int rem = p - od * HW;
    const int oh = rem / W, ow = rem - oh * W;
    const int ki = k / 9, kr2 = k - ki * 9;
    const int kj = kr2 / 3, kk = kr2 - kj * 3;

    float pd = (float)(od + ki - 1) + offd;
    float ph = (float)(oh + kj - 1) + offh;
    float pw = (float)(ow + kk - 1) + offw;

    float d0f = floorf(pd), h0f = floorf(ph), w0f = floorf(pw);
    float fd = pd - d0f, fh = ph - h0f, fw = pw - w0f;
    int d0 = (int)d0f, h0 = (int)h0f, w0 = (int)w0f;

    // ---- addresses first, then ALL 8 gathers issued back-to-back ----
    int dc0 = min(max(d0, 0), D - 1) * HW;
    int dc1 = min(max(d0 + 1, 0), D - 1) * HW;
    int hc0 = min(max(h0, 0), H - 1) * W;
    int hc1 = min(max(h0 + 1, 0), H - 1) * W;
    int wc0 = min(max(w0, 0), W - 1);
    int wc1 = min(max(w0 + 1, 0), W - 1);

    const u4* xb = reinterpret_cast<const u4*>(xt) + (size_t)b * SP * 2 + q;

    u4 v[8];
#pragma unroll
    for (int cn = 0; cn < 8; ++cn) {
        int idx = ((cn & 4) ? dc1 : dc0) + ((cn & 2) ? hc1 : hc0) + ((cn & 1) ? wc1 : wc0);
        v[cn] = xb[(size_t)idx * 2];
    }

    // ---- weights (VALU work overlaps the in-flight loads) ----
    bool vd0 = (d0 >= 0) & (d0 < D), vd1 = (d0 + 1 >= 0) & (d0 + 1 < D);
    bool vh0 = (h0 >= 0) & (h0 < H), vh1 = (h0 + 1 >= 0) & (h0 + 1 < H);
    bool vw0 = (w0 >= 0) & (w0 < W), vw1 = (w0 + 1 >= 0) & (w0 + 1 < W);
    float wd0 = 1.0f - fd, wd1 = fd;
    float wh0 = 1.0f - fh, wh1 = fh;
    float ww0 = 1.0f - fw, ww1 = fw;

    float wgt[8];
#pragma unroll
    for (int cn = 0; cn < 8; ++cn) {
        bool valid = ((cn & 4) ? vd1 : vd0) & ((cn & 2) ? vh1 : vh0) & ((cn & 1) ? vw1 : vw0);
        float wv2 = ((cn & 4) ? wd1 : wd0) * ((cn & 2) ? wh1 : wh0) * ((cn & 1) ? ww1 : ww0);
        wgt[cn] = valid ? wv2 : 0.0f;
    }

    f2 acc[4] = {};
#pragma unroll
    for (int cn = 0; cn < 8; ++cn) {
        f2 w2 = {wgt[cn], wgt[cn]};
#pragma unroll
        for (int m = 0; m < 4; ++m) {
            u32 wb = v[cn][m];
            f2 xv = {__builtin_bit_cast(float, wb << 16),
                     __builtin_bit_cast(float, wb & 0xffff0000u)};
            acc[m] += w2 * xv;
        }
    }

    // wave-local transpose -> 128B-line stores
    __shared__ float tile[4][16][36];
    const int wv = threadIdx.x >> 6;
#pragma unroll
    for (int m = 0; m < 4; ++m) {
        tile[wv][8 * q + 2 * m][c] = acc[m][0];
        tile[wv][8 * q + 2 * m + 1][c] = acc[m][1];
    }
    __syncthreads();

    const int p_base = p - c;                 // wave-uniform, 32-aligned
    const int ch_lo = l >> 3;                 // 0..7
    const int p0 = 4 * (l & 7);
    float* osb = out + ((size_t)b * C * K) * SP + p_base + p0;
#pragma unroll
    for (int rr = 0; rr < 2; ++rr) {
        int ch = 8 * rr + ch_lo;
        f4 vv = *reinterpret_cast<const f4*>(&tile[wv][ch][p0]);
        *reinterpret_cast<f4*>(osb + ((size_t)ch * K + k) * SP) = vv;
    }
}

// fallback (no workspace): one thread per sample, gather from native fp32 layout
__global__ __launch_bounds__(256) void deform_kernel_nat(const float* __restrict__ x,
                                                         const float* __restrict__ off,
                                                         float* __restrict__ out) {
    int tid = blockIdx.x * blockDim.x + threadIdx.x;
    if (tid >= B * K * SP) return;
    int p = tid % SP;
    int bk = tid / SP;
    int k = bk % K, b = bk / K;

    const float* ob = off + ((size_t)b * (3 * K) + 3 * k) * SP + p;
    float offd = ob[0];
    float offh = ob[(size_t)SP];
    float offw = ob[(size_t)2 * SP];

    int od = p / HW, rem = p - od * HW;
    int oh = rem / W, ow = rem - oh * W;
    int ki = k / 9, kr = k - ki * 9;
    int kj = kr / 3, kk = kr - kj * 3;

    float pd = (float)(od + ki - 1) + offd;
    float ph = (float)(oh + kj - 1) + offh;
    float pw = (float)(ow + kk - 1) + offw;

    float d0f = floorf(pd), h0f = floorf(ph), w0f = floorf(pw);
    float fd = pd - d0f, fh = ph - h0f, fw = pw - w0f;
    int d0 = (int)d0f, h0 = (int)h0f, w0 = (int)w0f;

    f4 acc[4] = {};
#pragma unroll
    for (int ci = 0; ci < 2; ++ci) {
        int ds = d0 + ci;
        bool vd = (ds >= 0) & (ds < D);
        float wd = ci ? fd : 1.0f - fd;
        int dc = min(max(ds, 0), D - 1);
#pragma unroll
        for (int cj = 0; cj < 2; ++cj) {
            int hs = h0 + cj;
            bool vh = (hs >= 0) & (hs < H);
            float wh = cj ? fh : 1.0f - fh;
            int hc = min(max(hs, 0), H - 1);
#pragma unroll
            for (int ck = 0; ck < 2; ++ck) {
                int ws = w0 + ck;
                bool vw = (ws >= 0) & (ws < W);
                float ww = ck ? fw : 1.0f - fw;
                int wc = min(max(ws, 0), W - 1);
                float wgt = (vd & vh & vw) ? wd * wh * ww : 0.0f;
                int idx = (dc * H + hc) * W + wc;
                const float* src = x + (size_t)b * C * SP + idx;
#pragma unroll
                for (int c2 = 0; c2 < C; ++c2)
                    acc[c2 >> 2][c2 & 3] += wgt * src[(size_t)c2 * SP];
            }
        }
    }

    float* o = out + ((size_t)b * C * K + k) * SP + p;
#pragma unroll
    for (int c2 = 0; c2 < C; ++c2)
        o[(size_t)c2 * K * SP] = acc[c2 >> 2][c2 & 3];
}

extern "C" void kernel_launch(void* const* d_in, const int* in_sizes, int n_in,
                              void* d_out, int out_size, void* d_ws, size_t ws_size,
                              hipStream_t stream) {
    const float* x = (const float*)d_in[0];
    const float* off = (const float*)d_in[1];
    float* out = (float*)d_out;

    const size_t xt_bytes = (size_t)B * SP * 16 * sizeof(ushort);  // 3.5 MB

    if (ws_size >= xt_bytes) {
        u32* xt = (u32*)d_ws;
        const int n_x = B * SP;
        xpose_bf16_kernel<<<(n_x + 255) / 256, 256, 0, stream>>>(x, xt);
        const long long n_thr = (long long)B * K * SP * 2;   // 5,971,968
        const int grid = (int)(n_thr / 256);                 // 23328, exact
        deform_bf16_v9<<<grid, 256, 0, stream>>>(xt, off, out);
    } else {
        const int n_main = B * K * SP;
        deform_kernel_nat<<<(n_main + 255) / 256, 256, 0, stream>>>(x, off, out);
    }
}